// Round 3
// baseline (272.493 us; speedup 1.0000x reference)
//
#include <hip/hip_runtime.h>

#define N_NODES 4096
#define KNN 9
#define CAPROW 128
#define THRESH 0.99f

__device__ __forceinline__ bool vi_greater(float av, int aj, float bv, int bj) {
  // order: larger value first; ties -> smaller index first (matches lax.top_k)
  return (av > bv) || (av == bv && aj < bj);
}

// Phase 1: streaming survivor collection. Also zeroes DV for the select phase.
__global__ __launch_bounds__(256) void collect_kernel(const float* __restrict__ dis,
                                                      float* __restrict__ svals,
                                                      int* __restrict__ scols,
                                                      int* __restrict__ scnt,
                                                      int* __restrict__ DV) {
  int gid = blockIdx.x * blockDim.x + threadIdx.x;
  if (gid < N_NODES) DV[gid] = 0;   // consumed by select (next dispatch)
  const int total4 = (N_NODES * N_NODES) / 4;
  const int stride = gridDim.x * blockDim.x;
  for (int i = gid; i < total4; i += stride) {
    float4 v = reinterpret_cast<const float4*>(dis)[i];
    int row = i >> 10;              // 1024 float4 per row
    int c0 = (i & 1023) * 4;
    float vals[4] = {v.x, v.y, v.z, v.w};
#pragma unroll
    for (int q = 0; q < 4; ++q) {
      int c = c0 + q;
      if (vals[q] > THRESH && c != row) {
        int p = atomicAdd(&scnt[row], 1);
        if (p < CAPROW) {
          svals[row * CAPROW + p] = vals[q];
          scols[row * CAPROW + p] = c;
        }
      }
    }
  }
}

// Phase 2: one wave per row. Fast path: exact top-9 over <=128 survivors
// (2 register entries/lane, 9 wave-argmax+pop rounds). Fallback: exact
// full-row scan (per-lane sorted top-9 + extraction) — statistically never.
__global__ __launch_bounds__(256) void select_kernel(const float* __restrict__ dis,
                                                     const float* __restrict__ svals,
                                                     const int* __restrict__ scols,
                                                     const int* __restrict__ scnt,
                                                     int* __restrict__ idx,
                                                     int* __restrict__ DV) {
  int wave = threadIdx.x >> 6;
  int lane = threadIdx.x & 63;
  int row = blockIdx.x * 4 + wave;
  int n = scnt[row];
  int outj[KNN];
  bool has_center = false;

  if (n >= KNN && n <= CAPROW) {
    float v0 = -3.0e38f, v1 = -3.0e38f;
    int c0 = 0x7fffffff, c1 = 0x7fffffff;
    int b = row * CAPROW + lane;
    if (lane < n)      { v0 = svals[b];      c0 = scols[b]; }
    if (lane + 64 < n) { v1 = svals[b + 64]; c1 = scols[b + 64]; }
#pragma unroll
    for (int rnd = 0; rnd < KNN; ++rnd) {
      bool first = vi_greater(v0, c0, v1, c1);
      float mv = first ? v0 : v1;
      int   mc = first ? c0 : c1;
#pragma unroll
      for (int d = 1; d < 64; d <<= 1) {
        float ov = __shfl_xor(mv, d);
        int   oc = __shfl_xor(mc, d);
        if (vi_greater(ov, oc, mv, mc)) { mv = ov; mc = oc; }
      }
      outj[rnd] = mc;
      if (c0 == mc) v0 = -3.3e38f;
      if (c1 == mc) v1 = -3.3e38f;
    }
    // survivors exclude the diagonal -> center never present
    outj[KNN - 1] = row;
  } else {
    // exact fallback over the full row
    const float* r = dis + (size_t)row * N_NODES;
    float v[9]; int ji[9];
#pragma unroll
    for (int t = 0; t < 9; ++t) { v[t] = -3.0e38f; ji[t] = 0x7fffffff; }
    for (int t = 0; t < 64; ++t) {
      int c = t * 64 + lane;
      float val = (c == row) ? -2.0e38f : r[c];
      if (vi_greater(val, c, v[8], ji[8])) {
        v[8] = val; ji[8] = c;
#pragma unroll
        for (int s = 8; s > 0; --s) {
          if (vi_greater(v[s], ji[s], v[s-1], ji[s-1])) {
            float tv = v[s]; v[s] = v[s-1]; v[s-1] = tv;
            int tj = ji[s]; ji[s] = ji[s-1]; ji[s-1] = tj;
          }
        }
      }
    }
#pragma unroll
    for (int rnd = 0; rnd < KNN; ++rnd) {
      float mv = v[0]; int mj = ji[0];
#pragma unroll
      for (int d = 1; d < 64; d <<= 1) {
        float ov = __shfl_xor(mv, d);
        int   oj = __shfl_xor(mj, d);
        if (vi_greater(ov, oj, mv, mj)) { mv = ov; mj = oj; }
      }
      outj[rnd] = mj;
      has_center = has_center || (mj == row);
      if (ji[0] == mj) {
#pragma unroll
        for (int s = 0; s < 8; ++s) { v[s] = v[s+1]; ji[s] = ji[s+1]; }
        v[8] = -3.0e38f; ji[8] = 0x7fffffff;
      }
    }
    if (!has_center) outj[KNN - 1] = row;
  }

  if (lane == 0) {
#pragma unroll
    for (int t = 0; t < KNN; ++t) {
      int j = outj[t];
      idx[row * KNN + t] = j;
      atomicAdd(&DV[j], 1);
    }
  }
}

// Single block: exclusive scan of DV -> off, dv2 = DV^-1/2, then CSR fill
// with the cursor kept in LDS.
__global__ __launch_bounds__(1024) void scan_fill(const int* __restrict__ DV,
                                                  const int* __restrict__ idx,
                                                  int* __restrict__ off,
                                                  float* __restrict__ dv2,
                                                  int* __restrict__ elist) {
  __shared__ int part[1024];
  __shared__ int cur[N_NODES];
  int tid = threadIdx.x;
  int vals[4]; int s = 0;
#pragma unroll
  for (int q = 0; q < 4; ++q) {
    int d = DV[tid * 4 + q];
    vals[q] = d; s += d;
    dv2[tid * 4 + q] = rsqrtf((float)d);
  }
  part[tid] = s;
  __syncthreads();
  for (int d = 1; d < 1024; d <<= 1) {
    int x = (tid >= d) ? part[tid - d] : 0;
    __syncthreads();
    part[tid] += x;
    __syncthreads();
  }
  int excl = (tid == 0) ? 0 : part[tid - 1];
#pragma unroll
  for (int q = 0; q < 4; ++q) {
    off[tid * 4 + q] = excl;
    cur[tid * 4 + q] = excl;
    excl += vals[q];
  }
  if (tid == 1023) off[N_NODES] = excl;
  __syncthreads();
  for (int t = tid; t < N_NODES * KNN; t += 1024) {
    int e = t / KNN;
    int node = idx[t];
    int p = atomicAdd(&cur[node], 1);
    elist[p] = e;
  }
}

// Stage A: Z[e,f] = (1/9) * sum_{j} dv2[idx[e][j]] * Y[idx[e][j], f]
template<int F>
__global__ __launch_bounds__(F) void edge_gather(const float* __restrict__ Y,
                                                 const int* __restrict__ idx,
                                                 const float* __restrict__ dv2,
                                                 float* __restrict__ Z) {
  __shared__ int er[KNN];
  __shared__ float ew[KNN];
  int e = blockIdx.x;
  if (threadIdx.x < KNN) {
    int r = idx[e * KNN + threadIdx.x];
    er[threadIdx.x] = r;
    ew[threadIdx.x] = dv2[r];
  }
  __syncthreads();
  int f = threadIdx.x;
  float acc = 0.f;
#pragma unroll
  for (int j = 0; j < KNN; ++j) acc += ew[j] * Y[(size_t)er[j] * F + f];
  Z[(size_t)e * F + f] = acc * (1.0f / 9.0f);
}

// Final stage B (no trailing GEMM): out[i,f] = relu(dv2[i] * sum Z[e,f])
template<int F>
__global__ __launch_bounds__(F) void node_gather(const float* __restrict__ Z,
                                                 const int* __restrict__ off,
                                                 const int* __restrict__ elist,
                                                 const float* __restrict__ dv2,
                                                 float* __restrict__ out) {
  int i = blockIdx.x;
  int f = threadIdx.x;
  int s = off[i], epos = off[i + 1];
  float acc = 0.f;
  for (int t = s; t < epos; ++t) acc += Z[(size_t)elist[t] * F + f];
  acc = fmaxf(acc * dv2[i], 0.f);
  out[(size_t)i * F + f] = acc;
}

// Dense P = Y @ W + bias ; ROWS rows per block, FO threads.
template<int KD, int FO, int ROWS>
__global__ __launch_bounds__(FO) void gemm_bias(const float* __restrict__ Y,
                                                const float* __restrict__ W,
                                                const float* __restrict__ bias,
                                                float* __restrict__ P) {
  __shared__ float ylds[ROWS * KD];
  int m0 = blockIdx.x * ROWS;
  for (int t = threadIdx.x; t < ROWS * KD / 4; t += FO)
    reinterpret_cast<float4*>(ylds)[t] =
        reinterpret_cast<const float4*>(Y + (size_t)m0 * KD)[t];
  __syncthreads();
  int f = threadIdx.x;
  float acc[ROWS];
#pragma unroll
  for (int rr = 0; rr < ROWS; ++rr) acc[rr] = 0.f;
  for (int k = 0; k < KD; k += 4) {
    float w0 = W[(size_t)(k + 0) * FO + f];
    float w1 = W[(size_t)(k + 1) * FO + f];
    float w2 = W[(size_t)(k + 2) * FO + f];
    float w3 = W[(size_t)(k + 3) * FO + f];
#pragma unroll
    for (int rr = 0; rr < ROWS; ++rr) {
      float4 y = *reinterpret_cast<const float4*>(&ylds[rr * KD + k]);
      acc[rr] = fmaf(y.x, w0, fmaf(y.y, w1, fmaf(y.z, w2, fmaf(y.w, w3, acc[rr]))));
    }
  }
  float bb = bias[f];
#pragma unroll
  for (int rr = 0; rr < ROWS; ++rr)
    P[(size_t)(m0 + rr) * FO + f] = acc[rr] + bb;
}

// Fused stage B + GEMM: h rows (relu'd node gather, width 128) built in LDS,
// then P = h @ W + bias. Optionally writes h to global (x1 output).
template<int FO, bool WRITE_H>
__global__ __launch_bounds__(FO) void node_gemm(const float* __restrict__ Z,
                                                const int* __restrict__ off,
                                                const int* __restrict__ elist,
                                                const float* __restrict__ dv2,
                                                const float* __restrict__ W,
                                                const float* __restrict__ bias,
                                                float* __restrict__ P,
                                                float* __restrict__ Hout) {
  constexpr int KD = 128;
  constexpr int ROWS = 8;
  __shared__ float ylds[ROWS * KD];
  int m0 = blockIdx.x * ROWS;
  for (int cell = threadIdx.x; cell < ROWS * KD; cell += FO) {
    int rr = cell >> 7, f = cell & 127;
    int i = m0 + rr;
    int s = off[i], epos = off[i + 1];
    float acc = 0.f;
    for (int t = s; t < epos; ++t) acc += Z[(size_t)elist[t] * KD + f];
    acc = fmaxf(acc * dv2[i], 0.f);
    ylds[cell] = acc;
    if (WRITE_H) Hout[(size_t)i * KD + f] = acc;
  }
  __syncthreads();
  int f = threadIdx.x;
  float acc[ROWS];
#pragma unroll
  for (int rr = 0; rr < ROWS; ++rr) acc[rr] = 0.f;
  for (int k = 0; k < KD; k += 4) {
    float w0 = W[(size_t)(k + 0) * FO + f];
    float w1 = W[(size_t)(k + 1) * FO + f];
    float w2 = W[(size_t)(k + 2) * FO + f];
    float w3 = W[(size_t)(k + 3) * FO + f];
#pragma unroll
    for (int rr = 0; rr < ROWS; ++rr) {
      float4 y = *reinterpret_cast<const float4*>(&ylds[rr * KD + k]);
      acc[rr] = fmaf(y.x, w0, fmaf(y.y, w1, fmaf(y.z, w2, fmaf(y.w, w3, acc[rr]))));
    }
  }
  float bb = bias[f];
#pragma unroll
  for (int rr = 0; rr < ROWS; ++rr)
    P[(size_t)(m0 + rr) * FO + f] = acc[rr] + bb;
}

extern "C" void kernel_launch(void* const* d_in, const int* in_sizes, int n_in,
                              void* d_out, int out_size, void* d_ws, size_t ws_size,
                              hipStream_t stream) {
  const float* x   = (const float*)d_in[0];
  const float* adj = (const float*)d_in[1];
  const float* W10 = (const float*)d_in[2];
  const float* b10 = (const float*)d_in[3];
  const float* W11 = (const float*)d_in[4];
  const float* b11 = (const float*)d_in[5];
  const float* W20 = (const float*)d_in[6];
  const float* b20 = (const float*)d_in[7];
  const float* W21 = (const float*)d_in[8];
  const float* b21 = (const float*)d_in[9];
  float* out = (float*)d_out;

  char* w = (char*)d_ws;
  int*   idx   = (int*)(w + 0);            // 147456
  int*   DV    = (int*)(w + 147456);       // 16384
  int*   off   = (int*)(w + 163840);       // 16640
  int*   scnt  = (int*)(w + 180480);       // 16384
  int*   elist = (int*)(w + 196864);       // 147456
  float* dv2   = (float*)(w + 344320);     // 16384
  float* svals = (float*)(w + 360704);     // 2 MB
  int*   scols = (int*)(w + 2457856);      // 2 MB
  float* bufP  = (float*)(w + 4555008);    // 4 MB
  float* bufZ  = (float*)(w + 8749312);    // 4 MB

  float* x1out = out + (size_t)N_NODES * 256;
  float* x2out = out + (size_t)N_NODES * 256 + (size_t)N_NODES * 128;

  hipMemsetAsync(scnt, 0, N_NODES * sizeof(int), stream);
  hipMemcpyAsync(out, x, (size_t)N_NODES * 256 * sizeof(float),
                 hipMemcpyDeviceToDevice, stream);

  // hypergraph construction
  collect_kernel<<<4096, 256, 0, stream>>>(adj, svals, scols, scnt, DV);
  select_kernel<<<N_NODES / 4, 256, 0, stream>>>(adj, svals, scols, scnt, idx, DV);
  scan_fill<<<1, 1024, 0, stream>>>(DV, idx, off, dv2, elist);

  // layer 1
  gemm_bias<256, 128, 8><<<N_NODES / 8, 128, 0, stream>>>(x, W10, b10, bufP);
  edge_gather<128><<<N_NODES, 128, 0, stream>>>(bufP, idx, dv2, bufZ);
  node_gemm<128, false><<<N_NODES / 8, 128, 0, stream>>>(bufZ, off, elist, dv2,
                                                         W11, b11, bufP, nullptr);
  edge_gather<128><<<N_NODES, 128, 0, stream>>>(bufP, idx, dv2, bufZ);
  // x1 = relu(node gather); fused with layer-2 first GEMM, also writes x1out
  node_gemm<128, true><<<N_NODES / 8, 128, 0, stream>>>(bufZ, off, elist, dv2,
                                                        W20, b20, bufP, x1out);
  // layer 2
  edge_gather<128><<<N_NODES, 128, 0, stream>>>(bufP, idx, dv2, bufZ);
  node_gemm<256, false><<<N_NODES / 8, 256, 0, stream>>>(bufZ, off, elist, dv2,
                                                         W21, b21, bufP, nullptr);
  edge_gather<256><<<N_NODES, 256, 0, stream>>>(bufP, idx, dv2, bufZ);
  node_gather<256><<<N_NODES, 256, 0, stream>>>(bufZ, off, elist, dv2, x2out);
}

// Round 4
// 195.165 us; speedup vs baseline: 1.3962x; 1.3962x over previous
//
#include <hip/hip_runtime.h>

#define N_NODES 4096
#define KNN 9
#define CAPE 32                 // max edges per node in the strided list
#define CAPW (CAPE * KNN)       // 288 entries per node
#define THRESH 0.99f

__device__ __forceinline__ bool vi_greater(float av, int aj, float bv, int bj) {
  // order: larger value first; ties -> smaller index first (matches lax.top_k)
  return (av > bv) || (av == bv && aj < bj);
}

// Fused top-k: one wave per row, 4 waves per block. Per-lane depth-9 sorted
// register list of survivors > THRESH; wave count-check with exact
// threshold-free rescan fallback; 9 wave-argmax+pop extraction rounds.
__global__ __launch_bounds__(256) void topk_kernel(const float* __restrict__ dis,
                                                   int* __restrict__ idx,
                                                   int* __restrict__ DV) {
  const int lane = threadIdx.x & 63;
  const int row = blockIdx.x * 4 + (threadIdx.x >> 6);
  const float4* r4 = reinterpret_cast<const float4*>(dis + (size_t)row * N_NODES);

  float v[9]; int c[9];
  float T = THRESH;
  int cnt = 0;

  for (int pass = 0; pass < 2; ++pass) {
#pragma unroll
    for (int t = 0; t < 9; ++t) { v[t] = -3.0e38f; c[t] = 0x7fffffff; }
    cnt = 0;
#pragma unroll 4
    for (int t = 0; t < 16; ++t) {
      float4 f4 = r4[t * 64 + lane];
      float vals[4] = {f4.x, f4.y, f4.z, f4.w};
      int cb = (t * 64 + lane) * 4;
#pragma unroll
      for (int q = 0; q < 4; ++q) {
        int cc = cb + q;
        float val = (cc == row) ? 0.0f : vals[q];   // ref zeroes the diagonal
        if (val > T) {
          ++cnt;
          if (vi_greater(val, cc, v[8], c[8])) {
            v[8] = val; c[8] = cc;
#pragma unroll
            for (int s = 8; s > 0; --s) {
              if (vi_greater(v[s], c[s], v[s-1], c[s-1])) {
                float tv = v[s]; v[s] = v[s-1]; v[s-1] = tv;
                int tc = c[s]; c[s] = c[s-1]; c[s-1] = tc;
              }
            }
          }
        }
      }
    }
    // wave-wide survivor count
    int total = cnt;
#pragma unroll
    for (int d = 1; d < 64; d <<= 1) total += __shfl_xor(total, d);
    if (total >= KNN) break;
    T = -3.0e38f;               // exact fallback: consider every element
  }

  // 9 extraction rounds over per-lane heads
  int outj[KNN];
  bool has_center = false;
#pragma unroll
  for (int rnd = 0; rnd < KNN; ++rnd) {
    float mv = v[0]; int mc = c[0];
#pragma unroll
    for (int d = 1; d < 64; d <<= 1) {
      float ov = __shfl_xor(mv, d);
      int   oc = __shfl_xor(mc, d);
      if (vi_greater(ov, oc, mv, mc)) { mv = ov; mc = oc; }
    }
    outj[rnd] = mc;
    has_center = has_center || (mc == row);
    if (c[0] == mc) {           // winner lane pops its head
#pragma unroll
      for (int s = 0; s < 8; ++s) { v[s] = v[s+1]; c[s] = c[s+1]; }
      v[8] = -3.0e38f; c[8] = 0x7fffffff;
    }
  }
  if (!has_center) outj[KNN - 1] = row;

  if (lane == 0) {
#pragma unroll
    for (int t = 0; t < KNN; ++t) {
      idx[row * KNN + t] = outj[t];
      atomicAdd(&DV[outj[t]], 1);
    }
  }
}

// dv2 = DV^-1/2 ; zero the wlist cursors.
__global__ void prep_kernel(const int* __restrict__ DV, float* __restrict__ dv2,
                            int* __restrict__ cur) {
  int i = blockIdx.x * blockDim.x + threadIdx.x;
  if (i < N_NODES) { dv2[i] = rsqrtf((float)DV[i]); cur[i] = 0; }
}

// For each edge e: its 9 members each receive the 9 member columns into their
// strided per-node list (order within a node's list is irrelevant: summed).
__global__ __launch_bounds__(128) void build_wlist(const int* __restrict__ idx,
                                                   int* __restrict__ cur,
                                                   int* __restrict__ wcol) {
  __shared__ int mem[KNN];
  __shared__ int base[KNN];
  int e = blockIdx.x;
  int t = threadIdx.x;
  if (t < KNN) mem[t] = idx[e * KNN + t];
  __syncthreads();
  if (t < KNN) {
    int b = atomicAdd(&cur[mem[t]], KNN);
    base[t] = (b + KNN <= CAPW) ? b : -1;   // overflow guard (P ~ 1e-11)
  }
  __syncthreads();
  if (t < KNN * KNN) {
    int a = t / KNN, b = t % KNN;
    if (base[a] >= 0)
      wcol[(size_t)mem[a] * CAPW + base[a] + b] = mem[b];
  }
}

// One-shot G-apply: out[i,f] = relu(dv2[i]/9 * sum_p dv2[col[p]] * Y[col[p], f])
template<int F>
__global__ __launch_bounds__(F) void gapply(const float* __restrict__ Y,
                                            const int* __restrict__ wcol,
                                            const int* __restrict__ wcnt,
                                            const float* __restrict__ dv2,
                                            float* __restrict__ out) {
  __shared__ int scol[CAPW];
  __shared__ float sw[CAPW];
  int i = blockIdx.x;
  int cnt = wcnt[i]; if (cnt > CAPW) cnt = CAPW;
  for (int t = threadIdx.x; t < cnt; t += F) {
    int cc = wcol[(size_t)i * CAPW + t];
    scol[t] = cc;
    sw[t] = dv2[cc];
  }
  __syncthreads();
  int f = threadIdx.x;
  float acc = 0.f;
#pragma unroll 4
  for (int p = 0; p < cnt; ++p)
    acc = fmaf(sw[p], Y[(size_t)scol[p] * F + f], acc);
  out[(size_t)i * F + f] = fmaxf(acc * dv2[i] * (1.0f / 9.0f), 0.f);
}

// Dense P = Y @ W + bias ; ROWS rows per block, FO threads (one output col each).
template<int KD, int FO, int ROWS>
__global__ __launch_bounds__(FO) void gemm_bias(const float* __restrict__ Y,
                                                const float* __restrict__ W,
                                                const float* __restrict__ bias,
                                                float* __restrict__ P) {
  __shared__ float ylds[ROWS * KD];
  int m0 = blockIdx.x * ROWS;
  for (int t = threadIdx.x; t < ROWS * KD / 4; t += FO)
    reinterpret_cast<float4*>(ylds)[t] =
        reinterpret_cast<const float4*>(Y + (size_t)m0 * KD)[t];
  __syncthreads();
  int f = threadIdx.x;
  float acc[ROWS];
#pragma unroll
  for (int rr = 0; rr < ROWS; ++rr) acc[rr] = 0.f;
  for (int k = 0; k < KD; k += 4) {
    float w0 = W[(size_t)(k + 0) * FO + f];
    float w1 = W[(size_t)(k + 1) * FO + f];
    float w2 = W[(size_t)(k + 2) * FO + f];
    float w3 = W[(size_t)(k + 3) * FO + f];
#pragma unroll
    for (int rr = 0; rr < ROWS; ++rr) {
      float4 y = *reinterpret_cast<const float4*>(&ylds[rr * KD + k]);
      acc[rr] = fmaf(y.x, w0, fmaf(y.y, w1, fmaf(y.z, w2, fmaf(y.w, w3, acc[rr]))));
    }
  }
  float bb = bias[f];
#pragma unroll
  for (int rr = 0; rr < ROWS; ++rr)
    P[(size_t)(m0 + rr) * FO + f] = acc[rr] + bb;
}

extern "C" void kernel_launch(void* const* d_in, const int* in_sizes, int n_in,
                              void* d_out, int out_size, void* d_ws, size_t ws_size,
                              hipStream_t stream) {
  const float* x   = (const float*)d_in[0];
  const float* adj = (const float*)d_in[1];
  const float* W10 = (const float*)d_in[2];
  const float* b10 = (const float*)d_in[3];
  const float* W11 = (const float*)d_in[4];
  const float* b11 = (const float*)d_in[5];
  const float* W20 = (const float*)d_in[6];
  const float* b20 = (const float*)d_in[7];
  const float* W21 = (const float*)d_in[8];
  const float* b21 = (const float*)d_in[9];
  float* out = (float*)d_out;

  char* w = (char*)d_ws;
  int*   idx  = (int*)(w + 0);            // 147456
  int*   DV   = (int*)(w + 147456);       // 16384
  int*   cur  = (int*)(w + 163840);       // 16384
  float* dv2  = (float*)(w + 180224);     // 16384
  int*   wcol = (int*)(w + 196608);       // 4096*288*4 = 4718592
  float* bufP = (float*)(w + 4915200);    // 4 MB
  float* bufH = (float*)(w + 9109504);    // 2 MB

  float* x1out = out + (size_t)N_NODES * 256;
  float* x2out = out + (size_t)N_NODES * 256 + (size_t)N_NODES * 128;

  hipMemsetAsync(DV, 0, N_NODES * sizeof(int), stream);
  hipMemcpyAsync(out, x, (size_t)N_NODES * 256 * sizeof(float),
                 hipMemcpyDeviceToDevice, stream);

  // hypergraph construction
  topk_kernel<<<N_NODES / 4, 256, 0, stream>>>(adj, idx, DV);
  prep_kernel<<<16, 256, 0, stream>>>(DV, dv2, cur);
  build_wlist<<<N_NODES, 128, 0, stream>>>(idx, cur, wcol);

  // layer 1
  gemm_bias<256, 128, 8><<<N_NODES / 8, 128, 0, stream>>>(x, W10, b10, bufP);
  gapply<128><<<N_NODES, 128, 0, stream>>>(bufP, wcol, cur, dv2, bufH);
  gemm_bias<128, 128, 8><<<N_NODES / 8, 128, 0, stream>>>(bufH, W11, b11, bufP);
  gapply<128><<<N_NODES, 128, 0, stream>>>(bufP, wcol, cur, dv2, x1out);

  // layer 2
  gemm_bias<128, 128, 8><<<N_NODES / 8, 128, 0, stream>>>(x1out, W20, b20, bufP);
  gapply<128><<<N_NODES, 128, 0, stream>>>(bufP, wcol, cur, dv2, bufH);
  gemm_bias<128, 256, 8><<<N_NODES / 8, 256, 0, stream>>>(bufH, W21, b21, bufP);
  gapply<256><<<N_NODES, 256, 0, stream>>>(bufP, wcol, cur, dv2, x2out);
}

// Round 5
// 153.570 us; speedup vs baseline: 1.7744x; 1.2709x over previous
//
#include <hip/hip_runtime.h>

#define N_NODES 4096
#define KNN 9
#define CAPS 128                // survivor capacity per row (2 per lane)
#define CAPE 32                 // max edges per node in the strided list
#define CAPW (CAPE * KNN)       // 288 entries per node
#define THRESH 0.99f

__device__ __forceinline__ bool vi_greater(float av, int aj, float bv, int bj) {
  // order: larger value first; ties -> smaller index first (matches lax.top_k)
  return (av > bv) || (av == bv && aj < bj);
}

// Top-k: one wave per row, 4 waves/block. Branchless ballot-compaction of
// survivors (> THRESH, off-diagonal) into per-wave LDS, then 8 wave-argmax
// rounds (9th slot is always the center node). Exact full-row fallback.
__global__ __launch_bounds__(256) void topk_kernel(const float* __restrict__ dis,
                                                   int* __restrict__ idx,
                                                   int* __restrict__ DV) {
  __shared__ float sval[4 * CAPS];
  __shared__ int   sidx[4 * CAPS];
  const int lane = threadIdx.x & 63;
  const int wv = threadIdx.x >> 6;
  const int row = blockIdx.x * 4 + wv;
  const float4* r4 = reinterpret_cast<const float4*>(dis + (size_t)row * N_NODES);
  float* wval = sval + wv * CAPS;
  int*   widx = sidx + wv * CAPS;
  const unsigned long long lmask = (1ull << lane) - 1;

  // phase 1: branch-free survivor compaction
  int n = 0;
#pragma unroll 4
  for (int t = 0; t < 16; ++t) {
    float4 f4 = r4[t * 64 + lane];
    float vals[4] = {f4.x, f4.y, f4.z, f4.w};
    int cb = (t * 64 + lane) * 4;
#pragma unroll
    for (int q = 0; q < 4; ++q) {
      int cc = cb + q;
      bool pred = (vals[q] > THRESH) && (cc != row);
      unsigned long long m = __ballot(pred);
      if (pred) {
        int p = n + __popcll(m & lmask);
        if (p < CAPS) { wval[p] = vals[q]; widx[p] = cc; }
      }
      n += __popcll(m);
    }
  }
  __syncthreads();

  int outj[KNN];
  if (n >= 8 && n <= CAPS) {
    // fast path: top-8 of survivors; slot 8 is the center (diagonal is zeroed
    // in the reference, so with >=8 survivors >0.99 the center is never in
    // the natural top-9 and always replaces the last slot).
    float v0 = -3.0e38f, v1 = -3.0e38f;
    int c0 = 0x7fffffff, c1 = 0x7fffffff;
    if (lane < n)      { v0 = wval[lane];      c0 = widx[lane]; }
    if (lane + 64 < n) { v1 = wval[lane + 64]; c1 = widx[lane + 64]; }
#pragma unroll
    for (int rnd = 0; rnd < 8; ++rnd) {
      bool first = vi_greater(v0, c0, v1, c1);
      float mv = first ? v0 : v1;
      int   mc = first ? c0 : c1;
#pragma unroll
      for (int d = 1; d < 64; d <<= 1) {
        float ov = __shfl_xor(mv, d);
        int   oc = __shfl_xor(mc, d);
        if (vi_greater(ov, oc, mv, mc)) { mv = ov; mc = oc; }
      }
      outj[rnd] = mc;
      if (c0 == mc) v0 = -3.3e38f;
      if (c1 == mc) v1 = -3.3e38f;
    }
    outj[8] = row;
  } else {
    // exact fallback: full-row per-lane sorted top-9 + 9 extraction rounds
    const float* r = dis + (size_t)row * N_NODES;
    float v[9]; int ji[9];
#pragma unroll
    for (int t = 0; t < 9; ++t) { v[t] = -3.0e38f; ji[t] = 0x7fffffff; }
    for (int t = 0; t < 64; ++t) {
      int cc = t * 64 + lane;
      float val = (cc == row) ? 0.0f : r[cc];
      if (vi_greater(val, cc, v[8], ji[8])) {
        v[8] = val; ji[8] = cc;
#pragma unroll
        for (int s = 8; s > 0; --s) {
          if (vi_greater(v[s], ji[s], v[s-1], ji[s-1])) {
            float tv = v[s]; v[s] = v[s-1]; v[s-1] = tv;
            int tj = ji[s]; ji[s] = ji[s-1]; ji[s-1] = tj;
          }
        }
      }
    }
    bool has_center = false;
#pragma unroll
    for (int rnd = 0; rnd < 9; ++rnd) {
      float mv = v[0]; int mj = ji[0];
#pragma unroll
      for (int d = 1; d < 64; d <<= 1) {
        float ov = __shfl_xor(mv, d);
        int   oj = __shfl_xor(mj, d);
        if (vi_greater(ov, oj, mv, mj)) { mv = ov; mj = oj; }
      }
      outj[rnd] = mj;
      has_center = has_center || (mj == row);
      if (ji[0] == mj) {
#pragma unroll
        for (int s = 0; s < 8; ++s) { v[s] = v[s+1]; ji[s] = ji[s+1]; }
        v[8] = -3.0e38f; ji[8] = 0x7fffffff;
      }
    }
    if (!has_center) outj[8] = row;
  }

  if (lane == 0) {
#pragma unroll
    for (int t = 0; t < KNN; ++t) {
      idx[row * KNN + t] = outj[t];
      atomicAdd(&DV[outj[t]], 1);
    }
  }
}

// dv2 = DV^-1/2 ; zero the wlist cursors.
__global__ void prep_kernel(const int* __restrict__ DV, float* __restrict__ dv2,
                            int* __restrict__ cur) {
  int i = blockIdx.x * blockDim.x + threadIdx.x;
  if (i < N_NODES) { dv2[i] = rsqrtf((float)DV[i]); cur[i] = 0; }
}

// For each edge e: its 9 members each receive the 9 member columns into their
// strided per-node list (order within a node's list is irrelevant: summed).
__global__ __launch_bounds__(128) void build_wlist(const int* __restrict__ idx,
                                                   int* __restrict__ cur,
                                                   int* __restrict__ wcol) {
  __shared__ int mem[KNN];
  __shared__ int base[KNN];
  int e = blockIdx.x;
  int t = threadIdx.x;
  if (t < KNN) mem[t] = idx[e * KNN + t];
  __syncthreads();
  if (t < KNN) {
    int b = atomicAdd(&cur[mem[t]], KNN);
    base[t] = (b + KNN <= CAPW) ? b : -1;   // overflow guard (P ~ 1e-11)
  }
  __syncthreads();
  if (t < KNN * KNN) {
    int a = t / KNN, b = t % KNN;
    if (base[a] >= 0)
      wcol[(size_t)mem[a] * CAPW + base[a] + b] = mem[b];
  }
}

// One-shot G-apply: out[i,f] = relu(dv2[i]/9 * sum_p dv2[col[p]] * Y[col[p], f])
template<int F>
__global__ __launch_bounds__(F) void gapply(const float* __restrict__ Y,
                                            const int* __restrict__ wcol,
                                            const int* __restrict__ wcnt,
                                            const float* __restrict__ dv2,
                                            float* __restrict__ out) {
  __shared__ int scol[CAPW];
  __shared__ float sw[CAPW];
  int i = blockIdx.x;
  int cnt = wcnt[i]; if (cnt > CAPW) cnt = CAPW;
  for (int t = threadIdx.x; t < cnt; t += F) {
    int cc = wcol[(size_t)i * CAPW + t];
    scol[t] = cc;
    sw[t] = dv2[cc];
  }
  __syncthreads();
  int f = threadIdx.x;
  float acc = 0.f;
#pragma unroll 4
  for (int p = 0; p < cnt; ++p)
    acc = fmaf(sw[p], Y[(size_t)scol[p] * F + f], acc);
  out[(size_t)i * F + f] = fmaxf(acc * dv2[i] * (1.0f / 9.0f), 0.f);
}

// Dense P = Y @ W + bias ; ROWS rows per block, FO threads (one output col each).
template<int KD, int FO, int ROWS>
__global__ __launch_bounds__(FO) void gemm_bias(const float* __restrict__ Y,
                                                const float* __restrict__ W,
                                                const float* __restrict__ bias,
                                                float* __restrict__ P) {
  __shared__ float ylds[ROWS * KD];
  int m0 = blockIdx.x * ROWS;
  for (int t = threadIdx.x; t < ROWS * KD / 4; t += FO)
    reinterpret_cast<float4*>(ylds)[t] =
        reinterpret_cast<const float4*>(Y + (size_t)m0 * KD)[t];
  __syncthreads();
  int f = threadIdx.x;
  float acc[ROWS];
#pragma unroll
  for (int rr = 0; rr < ROWS; ++rr) acc[rr] = 0.f;
  for (int k = 0; k < KD; k += 4) {
    float w0 = W[(size_t)(k + 0) * FO + f];
    float w1 = W[(size_t)(k + 1) * FO + f];
    float w2 = W[(size_t)(k + 2) * FO + f];
    float w3 = W[(size_t)(k + 3) * FO + f];
#pragma unroll
    for (int rr = 0; rr < ROWS; ++rr) {
      float4 y = *reinterpret_cast<const float4*>(&ylds[rr * KD + k]);
      acc[rr] = fmaf(y.x, w0, fmaf(y.y, w1, fmaf(y.z, w2, fmaf(y.w, w3, acc[rr]))));
    }
  }
  float bb = bias[f];
#pragma unroll
  for (int rr = 0; rr < ROWS; ++rr)
    P[(size_t)(m0 + rr) * FO + f] = acc[rr] + bb;
}

extern "C" void kernel_launch(void* const* d_in, const int* in_sizes, int n_in,
                              void* d_out, int out_size, void* d_ws, size_t ws_size,
                              hipStream_t stream) {
  const float* x   = (const float*)d_in[0];
  const float* adj = (const float*)d_in[1];
  const float* W10 = (const float*)d_in[2];
  const float* b10 = (const float*)d_in[3];
  const float* W11 = (const float*)d_in[4];
  const float* b11 = (const float*)d_in[5];
  const float* W20 = (const float*)d_in[6];
  const float* b20 = (const float*)d_in[7];
  const float* W21 = (const float*)d_in[8];
  const float* b21 = (const float*)d_in[9];
  float* out = (float*)d_out;

  char* w = (char*)d_ws;
  int*   idx  = (int*)(w + 0);            // 147456
  int*   DV   = (int*)(w + 147456);       // 16384
  int*   cur  = (int*)(w + 163840);       // 16384
  float* dv2  = (float*)(w + 180224);     // 16384
  int*   wcol = (int*)(w + 196608);       // 4096*288*4 = 4718592
  float* bufP = (float*)(w + 4915200);    // 4 MB
  float* bufH = (float*)(w + 9109504);    // 2 MB

  float* x1out = out + (size_t)N_NODES * 256;
  float* x2out = out + (size_t)N_NODES * 256 + (size_t)N_NODES * 128;

  hipMemsetAsync(DV, 0, N_NODES * sizeof(int), stream);
  hipMemcpyAsync(out, x, (size_t)N_NODES * 256 * sizeof(float),
                 hipMemcpyDeviceToDevice, stream);

  // hypergraph construction
  topk_kernel<<<N_NODES / 4, 256, 0, stream>>>(adj, idx, DV);
  prep_kernel<<<16, 256, 0, stream>>>(DV, dv2, cur);
  build_wlist<<<N_NODES, 128, 0, stream>>>(idx, cur, wcol);

  // layer 1
  gemm_bias<256, 128, 8><<<N_NODES / 8, 128, 0, stream>>>(x, W10, b10, bufP);
  gapply<128><<<N_NODES, 128, 0, stream>>>(bufP, wcol, cur, dv2, bufH);
  gemm_bias<128, 128, 8><<<N_NODES / 8, 128, 0, stream>>>(bufH, W11, b11, bufP);
  gapply<128><<<N_NODES, 128, 0, stream>>>(bufP, wcol, cur, dv2, x1out);

  // layer 2
  gemm_bias<128, 128, 8><<<N_NODES / 8, 128, 0, stream>>>(x1out, W20, b20, bufP);
  gapply<128><<<N_NODES, 128, 0, stream>>>(bufP, wcol, cur, dv2, bufH);
  gemm_bias<128, 256, 8><<<N_NODES / 8, 256, 0, stream>>>(bufH, W21, b21, bufP);
  gapply<256><<<N_NODES, 256, 0, stream>>>(bufP, wcol, cur, dv2, x2out);
}

// Round 6
// 134.417 us; speedup vs baseline: 2.0272x; 1.1425x over previous
//
#include <hip/hip_runtime.h>

#define N_NODES 4096
#define KNN 9
#define CAPS 128                // survivor capacity per row (2 per lane)
#define CAPE 32                 // max edges per node in strided elist
#define THRESH 0.99f

__device__ __forceinline__ bool vi_greater(float av, int aj, float bv, int bj) {
  // order: larger value first; ties -> smaller index first (matches lax.top_k)
  return (av > bv) || (av == bv && aj < bj);
}

// Zero DV and cur (replaces hipMemsetAsync: runtime fill cost ~40us in graph).
__global__ void zero_kernel(int* __restrict__ DV, int* __restrict__ cur) {
  int i = blockIdx.x * blockDim.x + threadIdx.x;
  if (i < N_NODES) { DV[i] = 0; cur[i] = 0; }
}

// Top-k: one wave per row, 4 waves/block. Branchless ballot-compaction of
// survivors (> THRESH, off-diagonal) into per-wave LDS, then 8 wave-argmax
// rounds (9th slot is always the center node). Exact full-row fallback.
__global__ __launch_bounds__(256) void topk_kernel(const float* __restrict__ dis,
                                                   int* __restrict__ idx,
                                                   int* __restrict__ DV) {
  __shared__ float sval[4 * CAPS];
  __shared__ int   sidx[4 * CAPS];
  const int lane = threadIdx.x & 63;
  const int wv = threadIdx.x >> 6;
  const int row = blockIdx.x * 4 + wv;
  const float4* r4 = reinterpret_cast<const float4*>(dis + (size_t)row * N_NODES);
  float* wval = sval + wv * CAPS;
  int*   widx = sidx + wv * CAPS;
  const unsigned long long lmask = (1ull << lane) - 1;

  // phase 1: branch-free survivor compaction
  int n = 0;
#pragma unroll 4
  for (int t = 0; t < 16; ++t) {
    float4 f4 = r4[t * 64 + lane];
    float vals[4] = {f4.x, f4.y, f4.z, f4.w};
    int cb = (t * 64 + lane) * 4;
#pragma unroll
    for (int q = 0; q < 4; ++q) {
      int cc = cb + q;
      bool pred = (vals[q] > THRESH) && (cc != row);
      unsigned long long m = __ballot(pred);
      if (pred) {
        int p = n + __popcll(m & lmask);
        if (p < CAPS) { wval[p] = vals[q]; widx[p] = cc; }
      }
      n += __popcll(m);
    }
  }
  __syncthreads();

  int outj[KNN];
  if (n >= 8 && n <= CAPS) {
    // fast path: top-8 of survivors; slot 8 is the center (diagonal zeroed in
    // the reference can never beat >=8 survivors above 0.99).
    float v0 = -3.0e38f, v1 = -3.0e38f;
    int c0 = 0x7fffffff, c1 = 0x7fffffff;
    if (lane < n)      { v0 = wval[lane];      c0 = widx[lane]; }
    if (lane + 64 < n) { v1 = wval[lane + 64]; c1 = widx[lane + 64]; }
#pragma unroll
    for (int rnd = 0; rnd < 8; ++rnd) {
      bool first = vi_greater(v0, c0, v1, c1);
      float mv = first ? v0 : v1;
      int   mc = first ? c0 : c1;
#pragma unroll
      for (int d = 1; d < 64; d <<= 1) {
        float ov = __shfl_xor(mv, d);
        int   oc = __shfl_xor(mc, d);
        if (vi_greater(ov, oc, mv, mc)) { mv = ov; mc = oc; }
      }
      outj[rnd] = mc;
      if (c0 == mc) v0 = -3.3e38f;
      if (c1 == mc) v1 = -3.3e38f;
    }
    outj[8] = row;
  } else {
    // exact fallback: full-row per-lane sorted top-9 + 9 extraction rounds
    const float* r = dis + (size_t)row * N_NODES;
    float v[9]; int ji[9];
#pragma unroll
    for (int t = 0; t < 9; ++t) { v[t] = -3.0e38f; ji[t] = 0x7fffffff; }
    for (int t = 0; t < 64; ++t) {
      int cc = t * 64 + lane;
      float val = (cc == row) ? 0.0f : r[cc];
      if (vi_greater(val, cc, v[8], ji[8])) {
        v[8] = val; ji[8] = cc;
#pragma unroll
        for (int s = 8; s > 0; --s) {
          if (vi_greater(v[s], ji[s], v[s-1], ji[s-1])) {
            float tv = v[s]; v[s] = v[s-1]; v[s-1] = tv;
            int tj = ji[s]; ji[s] = ji[s-1]; ji[s-1] = tj;
          }
        }
      }
    }
    bool has_center = false;
#pragma unroll
    for (int rnd = 0; rnd < 9; ++rnd) {
      float mv = v[0]; int mj = ji[0];
#pragma unroll
      for (int d = 1; d < 64; d <<= 1) {
        float ov = __shfl_xor(mv, d);
        int   oj = __shfl_xor(mj, d);
        if (vi_greater(ov, oj, mv, mj)) { mv = ov; mj = oj; }
      }
      outj[rnd] = mj;
      has_center = has_center || (mj == row);
      if (ji[0] == mj) {
#pragma unroll
        for (int s = 0; s < 8; ++s) { v[s] = v[s+1]; ji[s] = ji[s+1]; }
        v[8] = -3.0e38f; ji[8] = 0x7fffffff;
      }
    }
    if (!has_center) outj[8] = row;
  }

  if (lane == 0) {
#pragma unroll
    for (int t = 0; t < KNN; ++t) {
      idx[row * KNN + t] = outj[t];
      atomicAdd(&DV[outj[t]], 1);
    }
  }
}

// Strided inverse list: node -> edges containing it (cap CAPE, P(ovf)~1e-10).
__global__ void build_elist(const int* __restrict__ idx, int* __restrict__ cur,
                            int* __restrict__ elist) {
  int t = blockIdx.x * blockDim.x + threadIdx.x;
  if (t >= N_NODES * KNN) return;
  int e = t / KNN;
  int node = idx[t];
  int p = atomicAdd(&cur[node], 1);
  if (p < CAPE) elist[node * CAPE + p] = e;
}

// Stage A: Z[e,f] = (1/9) * sum_j DV[idx[e][j]]^-1/2 * Y[idx[e][j], f]
template<int F>
__global__ __launch_bounds__(F) void edge_gather(const float* __restrict__ Y,
                                                 const int* __restrict__ idx,
                                                 const int* __restrict__ DV,
                                                 float* __restrict__ Z) {
  __shared__ int er[KNN];
  __shared__ float ew[KNN];
  int e = blockIdx.x;
  if (threadIdx.x < KNN) {
    int r = idx[e * KNN + threadIdx.x];
    er[threadIdx.x] = r;
    ew[threadIdx.x] = rsqrtf((float)DV[r]);
  }
  __syncthreads();
  int f = threadIdx.x;
  float acc = 0.f;
#pragma unroll
  for (int j = 0; j < KNN; ++j)
    acc = fmaf(ew[j], Y[(size_t)er[j] * F + f], acc);
  Z[(size_t)e * F + f] = acc * (1.0f / 9.0f);
}

// Stage B: out[i,f] = relu(DV[i]^-1/2 * sum_{e in elist[i]} Z[e,f])
template<int F>
__global__ __launch_bounds__(F) void node_gather(const float* __restrict__ Z,
                                                 const int* __restrict__ elist,
                                                 const int* __restrict__ DV,
                                                 float* __restrict__ out) {
  int i = blockIdx.x;
  int f = threadIdx.x;
  int cnt = DV[i]; if (cnt > CAPE) cnt = CAPE;
  float acc = 0.f;
  for (int t = 0; t < cnt; ++t)
    acc += Z[(size_t)elist[i * CAPE + t] * F + f];
  out[(size_t)i * F + f] = fmaxf(acc * rsqrtf((float)DV[i]), 0.f);
}

// Dense P = Y @ W + bias ; ROWS rows per block, FO threads (one output col
// each). COPY: also write the staged Y rows to xcopy (x passthrough output).
template<int KD, int FO, int ROWS, bool COPY>
__global__ __launch_bounds__(FO) void gemm_bias(const float* __restrict__ Y,
                                                const float* __restrict__ W,
                                                const float* __restrict__ bias,
                                                float* __restrict__ P,
                                                float* __restrict__ xcopy) {
  __shared__ float ylds[ROWS * KD];
  int m0 = blockIdx.x * ROWS;
  for (int t = threadIdx.x; t < ROWS * KD / 4; t += FO) {
    float4 y4 = reinterpret_cast<const float4*>(Y + (size_t)m0 * KD)[t];
    reinterpret_cast<float4*>(ylds)[t] = y4;
    if (COPY) reinterpret_cast<float4*>(xcopy + (size_t)m0 * KD)[t] = y4;
  }
  __syncthreads();
  int f = threadIdx.x;
  float acc[ROWS];
#pragma unroll
  for (int rr = 0; rr < ROWS; ++rr) acc[rr] = 0.f;
  for (int k = 0; k < KD; k += 4) {
    float w0 = W[(size_t)(k + 0) * FO + f];
    float w1 = W[(size_t)(k + 1) * FO + f];
    float w2 = W[(size_t)(k + 2) * FO + f];
    float w3 = W[(size_t)(k + 3) * FO + f];
#pragma unroll
    for (int rr = 0; rr < ROWS; ++rr) {
      float4 y = *reinterpret_cast<const float4*>(&ylds[rr * KD + k]);
      acc[rr] = fmaf(y.x, w0, fmaf(y.y, w1, fmaf(y.z, w2, fmaf(y.w, w3, acc[rr]))));
    }
  }
  float bb = bias[f];
#pragma unroll
  for (int rr = 0; rr < ROWS; ++rr)
    P[(size_t)(m0 + rr) * FO + f] = acc[rr] + bb;
}

extern "C" void kernel_launch(void* const* d_in, const int* in_sizes, int n_in,
                              void* d_out, int out_size, void* d_ws, size_t ws_size,
                              hipStream_t stream) {
  const float* x   = (const float*)d_in[0];
  const float* adj = (const float*)d_in[1];
  const float* W10 = (const float*)d_in[2];
  const float* b10 = (const float*)d_in[3];
  const float* W11 = (const float*)d_in[4];
  const float* b11 = (const float*)d_in[5];
  const float* W20 = (const float*)d_in[6];
  const float* b20 = (const float*)d_in[7];
  const float* W21 = (const float*)d_in[8];
  const float* b21 = (const float*)d_in[9];
  float* out = (float*)d_out;

  char* w = (char*)d_ws;
  int*   idx   = (int*)(w + 0);            // 147456
  int*   DV    = (int*)(w + 147456);       // 16384
  int*   cur   = (int*)(w + 163840);       // 16384
  int*   elist = (int*)(w + 180224);       // 4096*32*4 = 524288
  float* bufP  = (float*)(w + 704512);     // 4 MB
  float* bufZ  = (float*)(w + 4898816);    // 4 MB
  float* bufH  = (float*)(w + 9093120);    // 2 MB

  float* x1out = out + (size_t)N_NODES * 256;
  float* x2out = out + (size_t)N_NODES * 256 + (size_t)N_NODES * 128;

  // hypergraph construction (no runtime fill/copy nodes)
  zero_kernel<<<16, 256, 0, stream>>>(DV, cur);
  topk_kernel<<<N_NODES / 4, 256, 0, stream>>>(adj, idx, DV);
  build_elist<<<(N_NODES * KNN + 255) / 256, 256, 0, stream>>>(idx, cur, elist);

  // layer 1 (gemm1 also emits the out=x passthrough)
  gemm_bias<256, 128, 8, true><<<N_NODES / 8, 128, 0, stream>>>(x, W10, b10, bufP, out);
  edge_gather<128><<<N_NODES, 128, 0, stream>>>(bufP, idx, DV, bufZ);
  node_gather<128><<<N_NODES, 128, 0, stream>>>(bufZ, elist, DV, bufH);
  gemm_bias<128, 128, 8, false><<<N_NODES / 8, 128, 0, stream>>>(bufH, W11, b11, bufP, nullptr);
  edge_gather<128><<<N_NODES, 128, 0, stream>>>(bufP, idx, DV, bufZ);
  node_gather<128><<<N_NODES, 128, 0, stream>>>(bufZ, elist, DV, x1out);

  // layer 2
  gemm_bias<128, 128, 8, false><<<N_NODES / 8, 128, 0, stream>>>(x1out, W20, b20, bufP, nullptr);
  edge_gather<128><<<N_NODES, 128, 0, stream>>>(bufP, idx, DV, bufZ);
  node_gather<128><<<N_NODES, 128, 0, stream>>>(bufZ, elist, DV, bufH);
  gemm_bias<128, 256, 8, false><<<N_NODES / 8, 256, 0, stream>>>(bufH, W21, b21, bufP, nullptr);
  edge_gather<256><<<N_NODES, 256, 0, stream>>>(bufP, idx, DV, bufZ);
  node_gather<256><<<N_NODES, 256, 0, stream>>>(bufZ, elist, DV, x2out);
}